// Round 4
// baseline (388.568 us; speedup 1.0000x reference)
//
#include <hip/hip_runtime.h>
#include <hip/hip_bf16.h>

// EdgeNetwork R4: barrier-free main kernel.
//  - Weights pre-transposed to bf16 image Wt[col][k] in d_ws (128 KB, L2-hot);
//    B-fragments loaded straight from global -> no weight LDS, NO __syncthreads.
//  - x pre-converted to bf16 (25.6 MB in d_ws) -> layer-0 A frags are direct
//    16-B loads (no f32->bf16 cvt in hot kernel).
//  - h tile (32 KB LDS) is wave-private rows -> no sync needed.
//  - 12 waves/CU target via __launch_bounds__(256,3).

typedef float f32x4 __attribute__((ext_vector_type(4)));
typedef __bf16 bf16x8 __attribute__((ext_vector_type(8)));
typedef unsigned int u32x4 __attribute__((ext_vector_type(4)));

#define MFMA16(a, b, c) __builtin_amdgcn_mfma_f32_16x16x32_bf16((a), (b), (c), 0, 0, 0)

static __device__ __forceinline__ unsigned short bf16bits(float f) {
  __bf16 h = (__bf16)f;
  return __builtin_bit_cast(unsigned short, h);
}

static __device__ __forceinline__ float tanh_fast(float t) {
  float ex = __expf(2.0f * t);
  return 1.0f - 2.0f * __builtin_amdgcn_rcpf(ex + 1.0f);
}

// ---- prep: x (f32) -> xb (bf16), vectorized ----
__global__ void prep_x(const float* __restrict__ x,
                       unsigned short* __restrict__ xb, int n8) {
  int gid = blockIdx.x * blockDim.x + threadIdx.x;
  const int stride = gridDim.x * blockDim.x;
  for (int i = gid; i < n8; i += stride) {
    const float4 a = ((const float4*)x)[i * 2];
    const float4 b = ((const float4*)x)[i * 2 + 1];
    u32x4 o;
    o[0] = (unsigned)bf16bits(a.x) | ((unsigned)bf16bits(a.y) << 16);
    o[1] = (unsigned)bf16bits(a.z) | ((unsigned)bf16bits(a.w) << 16);
    o[2] = (unsigned)bf16bits(b.x) | ((unsigned)bf16bits(b.y) << 16);
    o[3] = (unsigned)bf16bits(b.z) | ((unsigned)bf16bits(b.w) << 16);
    ((u32x4*)xb)[i] = o;
  }
}

// ---- prep: weights -> linear transposed bf16 image ----
// wt elems: [0,32768) Wt0[col][k0..255]; [32768,49152) Wt1[col][k0..127];
//           [49152,65536) Wt2[col][k0..127]
__global__ void prep_w(const float* __restrict__ W0, const float* __restrict__ W1,
                       const float* __restrict__ W2, unsigned short* __restrict__ wt) {
  const int gid = blockIdx.x * 256 + threadIdx.x;  // 65536 total
  if (gid < 32768) {
    const int k = gid >> 7, col = gid & 127;
    wt[col * 256 + k] = bf16bits(W0[k * 128 + col]);
  } else if (gid < 49152) {
    const int g = gid - 32768, k = g >> 7, col = g & 127;
    wt[32768 + col * 128 + k] = bf16bits(W1[k * 128 + col]);
  } else {
    const int g = gid - 49152, k = g >> 7, col = g & 127;
    wt[49152 + col * 128 + k] = bf16bits(W2[k * 128 + col]);
  }
}

// h tile: [row 0..127][col 0..127] bf16, byte ^= (row&7)<<4. Wave-private rows.
template <int XB>
__global__ __launch_bounds__(256, 3) void edge_mlp(
    const float* __restrict__ x, const int* __restrict__ ei,
    const float* __restrict__ B0, const float* __restrict__ B1,
    const float* __restrict__ B2,
    const float* __restrict__ W3, const float* __restrict__ B3,
    const float* __restrict__ G0, const float* __restrict__ Q0,
    const float* __restrict__ G1, const float* __restrict__ Q1,
    const float* __restrict__ G2, const float* __restrict__ Q2,
    const unsigned short* __restrict__ wt, const unsigned short* __restrict__ xb,
    float* __restrict__ out, int nE)
{
  __shared__ __align__(16) char lds[32768];
  const int tid  = threadIdx.x;
  const int lane = tid & 63;
  const int wv   = tid >> 6;
  const int row  = lane & 15;
  const int kgrp = lane >> 4;

  const int wbase = blockIdx.x * 128 + wv * 32;
  const int e0 = wbase + row;
  const int e1 = wbase + 16 + row;
  const int ec0 = e0 < nE ? e0 : nE - 1;
  const int ec1 = e1 < nE ? e1 : nE - 1;
  const int ns0 = ei[ec0], ne0 = ei[nE + ec0];
  const int ns1 = ei[ec1], ne1 = ei[nE + ec1];

  auto loadB = [&](int wbase_e, int K, int n, int kb) -> bf16x8 {
    return *(const bf16x8*)(wt + wbase_e + (n * 16 + row) * K + kb);
  };

  auto loadAl = [&](int rowl, int kg) -> bf16x8 {
    const int off = ((rowl * 128 + kg) * 2) ^ ((rowl & 7) << 4);
    return *(const bf16x8*)(lds + off);
  };

  // layer-0 A fragment: bf16 direct (XB) or f32 gather + cvt (fallback)
  auto loadA0 = [&](int node, int ko) -> bf16x8 {
    if (XB) {
      return *(const bf16x8*)(xb + (size_t)node * 128 + ko);
    } else {
      const float* src = x + (size_t)node * 128 + ko;
      const float4 ua = *(const float4*)(src);
      const float4 ub = *(const float4*)(src + 4);
      bf16x8 a;
      a[0] = (__bf16)ua.x; a[1] = (__bf16)ua.y; a[2] = (__bf16)ua.z; a[3] = (__bf16)ua.w;
      a[4] = (__bf16)ub.x; a[5] = (__bf16)ub.y; a[6] = (__bf16)ub.z; a[7] = (__bf16)ub.w;
      return a;
    }
  };

  f32x4 acc0[8], acc1[8];
  const f32x4 z4 = {0.f, 0.f, 0.f, 0.f};
  float bc[8], gc[8], qc[8];
  #pragma unroll
  for (int n = 0; n < 8; ++n) {
    const int c = n * 16 + row;
    bc[n] = B0[c]; gc[n] = G0[c]; qc[n] = Q0[c];
  }
  #pragma unroll
  for (int n = 0; n < 8; ++n) { acc0[n] = z4; acc1[n] = z4; }

  // ---- layer 0: K=256, A from gathered x, B from global wt ----
  #pragma unroll
  for (int u = 0; u < 8; ++u) {
    const int ko = (u & 3) * 32 + kgrp * 8;   // offset within the node row
    const int kb = u * 32 + kgrp * 8;         // k within W0
    const bf16x8 a0 = loadA0(u < 4 ? ns0 : ne0, ko);
    const bf16x8 a1 = loadA0(u < 4 ? ns1 : ne1, ko);
    #pragma unroll
    for (int n = 0; n < 8; ++n) {
      const bf16x8 b = loadB(0, 256, n, kb);
      acc0[n] = MFMA16(a0, b, acc0[n]);
      acc1[n] = MFMA16(a1, b, acc1[n]);
    }
  }

  // LN(+bias,g,q)+tanh -> bf16 h rows (wave-private; no barrier!)
  auto ln_store = [&](f32x4* acc, int rowbase) {
    float s1[4] = {0.f, 0.f, 0.f, 0.f};
    float s2[4] = {0.f, 0.f, 0.f, 0.f};
    #pragma unroll
    for (int n = 0; n < 8; ++n)
      #pragma unroll
      for (int r = 0; r < 4; ++r) {
        const float t = acc[n][r] + bc[n];
        acc[n][r] = t;
        s1[r] += t;
        s2[r] = __builtin_fmaf(t, t, s2[r]);
      }
    #pragma unroll
    for (int off = 1; off < 16; off <<= 1)
      #pragma unroll
      for (int r = 0; r < 4; ++r) {
        s1[r] += __shfl_xor(s1[r], off);
        s2[r] += __shfl_xor(s2[r], off);
      }
    #pragma unroll
    for (int r = 0; r < 4; ++r) {
      const float mu  = s1[r] * 0.0078125f;
      const float var = s2[r] * 0.0078125f - mu * mu;
      s1[r] = mu;
      s2[r] = __builtin_amdgcn_rsqf(var + 1e-5f);
    }
    #pragma unroll
    for (int n = 0; n < 8; ++n) {
      const int col = n * 16 + row;
      #pragma unroll
      for (int r = 0; r < 4; ++r) {
        const float k1 = s2[r] * gc[n];
        const float k0 = __builtin_fmaf(-s1[r], k1, qc[n]);
        const float th = tanh_fast(__builtin_fmaf(acc[n][r], k1, k0));
        const int rowl = rowbase + kgrp * 4 + r;
        const int off  = ((rowl * 128 + col) * 2) ^ ((rowl & 7) << 4);
        *(unsigned short*)(lds + off) = bf16bits(th);
      }
    }
  };

  ln_store(acc0, wv * 32);
  ln_store(acc1, wv * 32 + 16);

  // ---- layers 1 and 2: A from wave-private h tile, B from global wt ----
  auto layer = [&](int welems, int Bcount) {
    #pragma unroll
    for (int n = 0; n < 8; ++n) { acc0[n] = z4; acc1[n] = z4; }
    #pragma unroll
    for (int u = 0; u < 4; ++u) {
      const int kb = u * 32 + kgrp * 8;
      const bf16x8 a0 = loadAl(wv * 32 + row, kb);
      const bf16x8 a1 = loadAl(wv * 32 + 16 + row, kb);
      #pragma unroll
      for (int n = 0; n < 8; ++n) {
        const bf16x8 b = loadB(welems, 128, n, kb);
        acc0[n] = MFMA16(a0, b, acc0[n]);
        acc1[n] = MFMA16(a1, b, acc1[n]);
      }
    }
    (void)Bcount;
  };

  #pragma unroll
  for (int n = 0; n < 8; ++n) {
    const int c = n * 16 + row;
    bc[n] = B1[c]; gc[n] = G1[c]; qc[n] = Q1[c];
  }
  layer(32768, 128);
  ln_store(acc0, wv * 32);
  ln_store(acc1, wv * 32 + 16);

  #pragma unroll
  for (int n = 0; n < 8; ++n) {
    const int c = n * 16 + row;
    bc[n] = B2[c]; gc[n] = G2[c]; qc[n] = Q2[c];
  }
  layer(49152, 128);

  // ---- final: LN + tanh + dot W3 + b3 ----
  float w3c[8];
  #pragma unroll
  for (int n = 0; n < 8; ++n) w3c[n] = W3[n * 16 + row];
  const float b3v = B3[0];

  auto ln_dot = [&](f32x4* acc, int ebase) {
    float s1[4] = {0.f, 0.f, 0.f, 0.f};
    float s2[4] = {0.f, 0.f, 0.f, 0.f};
    #pragma unroll
    for (int n = 0; n < 8; ++n)
      #pragma unroll
      for (int r = 0; r < 4; ++r) {
        const float t = acc[n][r] + bc[n];
        acc[n][r] = t;
        s1[r] += t;
        s2[r] = __builtin_fmaf(t, t, s2[r]);
      }
    #pragma unroll
    for (int off = 1; off < 16; off <<= 1)
      #pragma unroll
      for (int r = 0; r < 4; ++r) {
        s1[r] += __shfl_xor(s1[r], off);
        s2[r] += __shfl_xor(s2[r], off);
      }
    float d[4];
    #pragma unroll
    for (int r = 0; r < 4; ++r) {
      const float mu  = s1[r] * 0.0078125f;
      const float var = s2[r] * 0.0078125f - mu * mu;
      s1[r] = mu;
      s2[r] = __builtin_amdgcn_rsqf(var + 1e-5f);
      d[r] = 0.f;
    }
    #pragma unroll
    for (int n = 0; n < 8; ++n)
      #pragma unroll
      for (int r = 0; r < 4; ++r) {
        const float k1 = s2[r] * gc[n];
        const float k0 = __builtin_fmaf(-s1[r], k1, qc[n]);
        const float t  = __builtin_fmaf(acc[n][r], k1, k0);
        d[r] = __builtin_fmaf(tanh_fast(t), w3c[n], d[r]);
      }
    #pragma unroll
    for (int off = 1; off < 16; off <<= 1)
      #pragma unroll
      for (int r = 0; r < 4; ++r)
        d[r] += __shfl_xor(d[r], off);
    #pragma unroll
    for (int r = 0; r < 4; ++r) {
      const int e = ebase + kgrp * 4 + r;
      if (row == r && e < nE) out[e] = d[r] + b3v;
    }
  };

  ln_dot(acc0, wbase);
  ln_dot(acc1, wbase + 16);
}

extern "C" void kernel_launch(void* const* d_in, const int* in_sizes, int n_in,
                              void* d_out, int out_size, void* d_ws, size_t ws_size,
                              hipStream_t stream) {
  const float* x  = (const float*)d_in[0];
  const int*   ei = (const int*)d_in[1];
  const float* W0 = (const float*)d_in[2];
  const float* B0 = (const float*)d_in[3];
  const float* W1 = (const float*)d_in[4];
  const float* B1 = (const float*)d_in[5];
  const float* W2 = (const float*)d_in[6];
  const float* B2 = (const float*)d_in[7];
  const float* W3 = (const float*)d_in[8];
  const float* B3 = (const float*)d_in[9];
  const float* G0 = (const float*)d_in[10];
  const float* Q0 = (const float*)d_in[11];
  const float* G1 = (const float*)d_in[12];
  const float* Q1 = (const float*)d_in[13];
  const float* G2 = (const float*)d_in[14];
  const float* Q2 = (const float*)d_in[15];
  float* out = (float*)d_out;

  const int nX = in_sizes[0];           // 12.8M floats
  const int nE = in_sizes[1] / 2;
  const int blocks = (nE + 127) / 128;

  const size_t woff = ((size_t)nX * 2 + 255) & ~(size_t)255;
  const int use_xb = (ws_size >= woff + 131072) ? 1 : 0;
  unsigned short* wt = use_xb ? (unsigned short*)((char*)d_ws + woff)
                              : (unsigned short*)d_ws;
  unsigned short* xbp = (unsigned short*)d_ws;

  hipLaunchKernelGGL(prep_w, dim3(256), dim3(256), 0, stream, W0, W1, W2, wt);
  if (use_xb) {
    const int n8 = nX / 8;
    hipLaunchKernelGGL(prep_x, dim3(2048), dim3(256), 0, stream, x, xbp, n8);
    hipLaunchKernelGGL(edge_mlp<1>, dim3(blocks), dim3(256), 0, stream,
                       x, ei, B0, B1, B2, W3, B3, G0, Q0, G1, Q1, G2, Q2,
                       wt, xbp, out, nE);
  } else {
    hipLaunchKernelGGL(edge_mlp<0>, dim3(blocks), dim3(256), 0, stream,
                       x, ei, B0, B1, B2, W3, B3, G0, Q0, G1, Q1, G2, Q2,
                       wt, xbp, out, nE);
  }
}

// Round 5
// 198.549 us; speedup vs baseline: 1.9570x; 1.9570x over previous
//
#include <hip/hip_runtime.h>
#include <hip/hip_bf16.h>

// EdgeNetwork R5: transposed-GEMM convention (M=out-channels, N=edges) with
// K-permuted weights so the hidden state stays in registers across layers.
//  - mfma(Wfrag, xfrag): D col(lane&15)=edge, row(g*4+r)=out-channel.
//  - Lane (e,g) holds channels {m*16+g*4+r}. Next layer needs lane g to
//    supply k=g*8+j; pre-permuting W1/W2 rows by k -> (j>>2)*16+g*4+(j&3)
//    (within 32-blocks) makes those exactly the lane-held channels: the
//    packed bf16 pairs ARE the next B-fragment. No LDS h-tile, no shuffles.
//  - Weights staged to LDS (swizzled image via global_load_lds, R3-verified).
//  - Bias folded into acc init; b/g/q/W3 in a 5 KB LDS param block.
//  - LDS 38 KB -> 4 blocks/CU (16 waves/CU vs R3's 8).

typedef float f32x4 __attribute__((ext_vector_type(4)));
typedef __bf16 bf16x8 __attribute__((ext_vector_type(8)));
typedef unsigned int u32x4 __attribute__((ext_vector_type(4)));

#define MFMA16(a, b, c) __builtin_amdgcn_mfma_f32_16x16x32_bf16((a), (b), (c), 0, 0, 0)

static __device__ __forceinline__ unsigned short bf16bits(float f) {
  __bf16 h = (__bf16)f;
  return __builtin_bit_cast(unsigned short, h);
}

static __device__ __forceinline__ unsigned pack2(float a, float b) {
  return (unsigned)bf16bits(a) | ((unsigned)bf16bits(b) << 16);
}

static __device__ __forceinline__ float tanh_fast(float t) {
  float ex = __expf(2.0f * t);
  return 1.0f - 2.0f * __builtin_amdgcn_rcpf(ex + 1.0f);
}

static __device__ __forceinline__ void gload_lds16(const void* g, void* l) {
  __builtin_amdgcn_global_load_lds(
      (const __attribute__((address_space(1))) void*)g,
      (__attribute__((address_space(3))) void*)l, 16, 0, 0);
}

// K-row permutation for layer>=1 weights (within each 32-row block):
// k = blk + g*8 + j  ->  blk + (j>>2)*16 + g*4 + (j&3)
static __device__ __forceinline__ int permk(int k) {
  const int j = k & 7, g = (k >> 3) & 3;
  return (k & ~31) | ((j >> 2) << 4) | (g << 2) | (j & 3);
}

// ---- prep: x (f32) -> xb (bf16) ----
__global__ void prep_x(const float* __restrict__ x,
                       unsigned short* __restrict__ xb, int n8) {
  int gid = blockIdx.x * blockDim.x + threadIdx.x;
  const int stride = gridDim.x * blockDim.x;
  for (int i = gid; i < n8; i += stride) {
    const float4 a = ((const float4*)x)[i * 2];
    const float4 b = ((const float4*)x)[i * 2 + 1];
    u32x4 o;
    o[0] = pack2(a.x, a.y); o[1] = pack2(a.z, a.w);
    o[2] = pack2(b.x, b.y); o[3] = pack2(b.z, b.w);
    ((u32x4*)xb)[i] = o;
  }
}

// ---- prep: weight slabs (swizzled, K-permuted for W1/W2) + param block ----
// Slab t in [0,8): 16384 B at wt+t*8192 (ushort elems). t0-3=W0, t4-5=W1,
// t6-7=W2. Byte ((col*64+kl)*2)^((col&7)<<4) holds W[c(k)][col], k=t*64+kl.
// Block 8: params pp[1280] = B0,G0,Q0,B1,G1,Q1,B2,G2,Q2,W3 (128 f32 each).
__global__ void prep_w(const float* __restrict__ W0, const float* __restrict__ W1,
                       const float* __restrict__ W2,
                       const float* __restrict__ B0, const float* __restrict__ G0,
                       const float* __restrict__ Q0,
                       const float* __restrict__ B1, const float* __restrict__ G1,
                       const float* __restrict__ Q1,
                       const float* __restrict__ B2, const float* __restrict__ G2,
                       const float* __restrict__ Q2,
                       const float* __restrict__ W3,
                       unsigned short* __restrict__ wt, float* __restrict__ pp) {
  const int t = blockIdx.x;
  const int tid = threadIdx.x;
  if (t == 8) {
    for (int i = tid; i < 1280; i += 256) {
      const int a = i >> 7, o = i & 127;
      float v;
      switch (a) {
        case 0: v = B0[o]; break;  case 1: v = G0[o]; break;
        case 2: v = Q0[o]; break;  case 3: v = B1[o]; break;
        case 4: v = G1[o]; break;  case 5: v = Q1[o]; break;
        case 6: v = B2[o]; break;  case 7: v = G2[o]; break;
        case 8: v = Q2[o]; break;  default: v = W3[o]; break;
      }
      pp[i] = v;
    }
    return;
  }
  const float* src; int kbase; int perm;
  if (t < 4)      { src = W0; kbase = t * 64;      perm = 0; }
  else if (t < 6) { src = W1; kbase = (t - 4) * 64; perm = 1; }
  else            { src = W2; kbase = (t - 6) * 64; perm = 1; }
  char* base = (char*)wt + t * 16384;
  const int col = tid & 127;
  const int kb  = (tid >> 7) << 1;
  #pragma unroll
  for (int i = 0; i < 16; ++i) {
    const int kl = kb + (i << 2);
    const int k0 = kbase + kl;
    const int c0 = perm ? permk(k0) : k0;  // c(k0+1) == c0+1 (k0 even)
    const float wa = src[c0 * 128 + col];
    const float wb = src[(c0 + 1) * 128 + col];
    const unsigned pk = pack2(wa, wb);
    const int off = ((col * 64 + kl) * 2) ^ ((col & 7) << 4);
    *(unsigned*)(base + off) = pk;
  }
}

// Param base indices in LDS f32 block:
#define P_B0 0
#define P_G0 128
#define P_Q0 256
#define P_B1 384
#define P_G1 512
#define P_Q1 640
#define P_B2 768
#define P_G2 896
#define P_Q2 1024
#define P_W3 1152

template <int XB>
__global__ __launch_bounds__(256, 4) void edge_mlp(
    const float* __restrict__ x, const int* __restrict__ ei,
    const float* __restrict__ B3,
    const unsigned short* __restrict__ wt, const float* __restrict__ pp,
    const unsigned short* __restrict__ xb,
    float* __restrict__ out, int nE)
{
  __shared__ __align__(16) char lds[32768 + 5120];
  float* plds = (float*)(lds + 32768);
  const int tid  = threadIdx.x;
  const int lane = tid & 63;
  const int wv   = tid >> 6;
  const int e    = lane & 15;  // edge within tile (N dim)
  const int g    = lane >> 4;  // k-group / accumulator row group

  const int wbase = blockIdx.x * 128 + wv * 32;
  const int e0 = wbase + e;
  const int e1 = wbase + 16 + e;
  const int ec0 = e0 < nE ? e0 : nE - 1;
  const int ec1 = e1 < nE ? e1 : nE - 1;
  const int ns0 = ei[ec0], ne0 = ei[nE + ec0];
  const int ns1 = ei[ec1], ne1 = ei[nE + ec1];

  auto stageW = [&](int t, int buf) {
    #pragma unroll
    for (int c = 0; c < 4; ++c) {
      const int o = wv * 4096 + c * 1024;
      gload_lds16((const char*)wt + t * 16384 + o + lane * 16,
                  lds + buf * 16384 + o);
    }
  };

  auto loadW = [&](int buf, int m, int kl) -> bf16x8 {
    const int col = m * 16 + e;
    const int off = ((col * 64 + kl) * 2) ^ ((col & 7) << 4);
    return *(const bf16x8*)(lds + buf * 16384 + off);
  };

  auto loadX = [&](int node, int ko) -> bf16x8 {
    if (XB) {
      return *(const bf16x8*)(xb + (size_t)node * 128 + ko);
    } else {
      const float* src = x + (size_t)node * 128 + ko;
      const float4 ua = *(const float4*)(src);
      const float4 ub = *(const float4*)(src + 4);
      bf16x8 a;
      a[0] = (__bf16)ua.x; a[1] = (__bf16)ua.y; a[2] = (__bf16)ua.z; a[3] = (__bf16)ua.w;
      a[4] = (__bf16)ub.x; a[5] = (__bf16)ub.y; a[6] = (__bf16)ub.z; a[7] = (__bf16)ub.w;
      return a;
    }
  };

  f32x4 acc[8][2];

  auto initAcc = [&](int pb) {
    #pragma unroll
    for (int m = 0; m < 8; ++m) {
      const f32x4 bq = *(const f32x4*)(plds + pb + m * 16 + g * 4);
      acc[m][0] = bq; acc[m][1] = bq;
    }
  };

  // Layer 0 double k-step: u0 in {0,2,4,6}, slab buf holds k=u0*32..u0*32+63.
  auto l0step = [&](int u0, int buf) {
    #pragma unroll
    for (int du = 0; du < 2; ++du) {
      const int u = u0 + du;
      const int ko = (u & 3) * 32 + g * 8;
      const bf16x8 xf0 = loadX(u < 4 ? ns0 : ne0, ko);
      const bf16x8 xf1 = loadX(u < 4 ? ns1 : ne1, ko);
      const int kl = du * 32 + g * 8;
      #pragma unroll
      for (int m = 0; m < 8; ++m) {
        const bf16x8 wf = loadW(buf, m, kl);
        acc[m][0] = MFMA16(wf, xf0, acc[m][0]);
        acc[m][1] = MFMA16(wf, xf1, acc[m][1]);
      }
    }
  };

  // Packed hidden state: p0/p1[j][m] = bf16 pairs (r0,r1)/(r2,r3) of block m.
  unsigned p0[2][8], p1[2][8];

  // LN + tanh + pack (consumes acc; all in registers).
  auto epi = [&](int pg, int pq) {
    #pragma unroll
    for (int j = 0; j < 2; ++j) {
      float s1 = 0.f, s2 = 0.f;
      #pragma unroll
      for (int m = 0; m < 8; ++m)
        #pragma unroll
        for (int r = 0; r < 4; ++r) {
          const float t = acc[m][j][r];
          s1 += t;
          s2 = __builtin_fmaf(t, t, s2);
        }
      s1 += __shfl_xor(s1, 16); s2 += __shfl_xor(s2, 16);
      s1 += __shfl_xor(s1, 32); s2 += __shfl_xor(s2, 32);
      const float mu  = s1 * 0.0078125f;
      const float inv = __builtin_amdgcn_rsqf(s2 * 0.0078125f - mu * mu + 1e-5f);
      #pragma unroll
      for (int m = 0; m < 8; ++m) {
        const f32x4 gq = *(const f32x4*)(plds + pg + m * 16 + g * 4);
        const f32x4 qq = *(const f32x4*)(plds + pq + m * 16 + g * 4);
        float th[4];
        #pragma unroll
        for (int r = 0; r < 4; ++r) {
          const float y = __builtin_fmaf(acc[m][j][r] - mu, inv * gq[r], qq[r]);
          th[r] = tanh_fast(y);
        }
        p0[j][m] = pack2(th[0], th[1]);
        p1[j][m] = pack2(th[2], th[3]);
      }
    }
  };

  // Layers 1/2 double k-step: B-fragments are register concats of p words.
  auto lstep = [&](int u0, int buf) {
    #pragma unroll
    for (int du = 0; du < 2; ++du) {
      const int u = u0 + du;
      const int kl = du * 32 + g * 8;
      u32x4 w0, w1;
      w0[0] = p0[0][2 * u];     w0[1] = p1[0][2 * u];
      w0[2] = p0[0][2 * u + 1]; w0[3] = p1[0][2 * u + 1];
      w1[0] = p0[1][2 * u];     w1[1] = p1[1][2 * u];
      w1[2] = p0[1][2 * u + 1]; w1[3] = p1[1][2 * u + 1];
      const bf16x8 bf0 = __builtin_bit_cast(bf16x8, w0);
      const bf16x8 bf1 = __builtin_bit_cast(bf16x8, w1);
      #pragma unroll
      for (int m = 0; m < 8; ++m) {
        const bf16x8 wf = loadW(buf, m, kl);
        acc[m][0] = MFMA16(wf, bf0, acc[m][0]);
        acc[m][1] = MFMA16(wf, bf1, acc[m][1]);
      }
    }
  };

  // ---------------- schedule (8 barriers, dbuf slabs) ----------------
  stageW(0, 0);
  for (int i = tid; i < 1280; i += 256) plds[i] = pp[i];
  __syncthreads();

  initAcc(P_B0);
  stageW(1, 1); l0step(0, 0); __syncthreads();
  stageW(2, 0); l0step(2, 1); __syncthreads();
  stageW(3, 1); l0step(4, 0); __syncthreads();
  stageW(4, 0); l0step(6, 1); __syncthreads();            // buf0 <- W1 k0-63
  stageW(5, 1);                                            // buf1 <- W1 k64-127
  epi(P_G0, P_Q0); initAcc(P_B1); lstep(0, 0); __syncthreads();
  stageW(6, 0);                                            // buf0 <- W2 k0-63
  lstep(2, 1); __syncthreads();
  stageW(7, 1);                                            // buf1 <- W2 k64-127
  epi(P_G1, P_Q1); initAcc(P_B2); lstep(0, 0); __syncthreads();
  lstep(2, 1);

  // ---- final: LN + tanh + dot W3 + b3, all in registers ----
  const float b3v = B3[0];
  #pragma unroll
  for (int j = 0; j < 2; ++j) {
    float s1 = 0.f, s2 = 0.f;
    #pragma unroll
    for (int m = 0; m < 8; ++m)
      #pragma unroll
      for (int r = 0; r < 4; ++r) {
        const float t = acc[m][j][r];
        s1 += t;
        s2 = __builtin_fmaf(t, t, s2);
      }
    s1 += __shfl_xor(s1, 16); s2 += __shfl_xor(s2, 16);
    s1 += __shfl_xor(s1, 32); s2 += __shfl_xor(s2, 32);
    const float mu  = s1 * 0.0078125f;
    const float inv = __builtin_amdgcn_rsqf(s2 * 0.0078125f - mu * mu + 1e-5f);
    float d = 0.f;
    #pragma unroll
    for (int m = 0; m < 8; ++m) {
      const f32x4 gq  = *(const f32x4*)(plds + P_G2 + m * 16 + g * 4);
      const f32x4 qq  = *(const f32x4*)(plds + P_Q2 + m * 16 + g * 4);
      const f32x4 w3q = *(const f32x4*)(plds + P_W3 + m * 16 + g * 4);
      #pragma unroll
      for (int r = 0; r < 4; ++r) {
        const float y = __builtin_fmaf(acc[m][j][r] - mu, inv * gq[r], qq[r]);
        d = __builtin_fmaf(tanh_fast(y), w3q[r], d);
      }
    }
    d += __shfl_xor(d, 16);
    d += __shfl_xor(d, 32);
    const int eid = wbase + j * 16 + e;
    if (g == 0 && eid < nE) out[eid] = d + b3v;
  }
}

extern "C" void kernel_launch(void* const* d_in, const int* in_sizes, int n_in,
                              void* d_out, int out_size, void* d_ws, size_t ws_size,
                              hipStream_t stream) {
  const float* x  = (const float*)d_in[0];
  const int*   ei = (const int*)d_in[1];
  const float* W0 = (const float*)d_in[2];
  const float* B0 = (const float*)d_in[3];
  const float* W1 = (const float*)d_in[4];
  const float* B1 = (const float*)d_in[5];
  const float* W2 = (const float*)d_in[6];
  const float* B2 = (const float*)d_in[7];
  const float* W3 = (const float*)d_in[8];
  const float* B3 = (const float*)d_in[9];
  const float* G0 = (const float*)d_in[10];
  const float* Q0 = (const float*)d_in[11];
  const float* G1 = (const float*)d_in[12];
  const float* Q1 = (const float*)d_in[13];
  const float* G2 = (const float*)d_in[14];
  const float* Q2 = (const float*)d_in[15];
  float* out = (float*)d_out;

  const int nX = in_sizes[0];
  const int nE = in_sizes[1] / 2;
  const int blocks = (nE + 127) / 128;

  const size_t xb_bytes = ((size_t)nX * 2 + 255) & ~(size_t)255;
  const int use_xb = (ws_size >= xb_bytes + 131072 + 5120) ? 1 : 0;

  unsigned short* xbp = (unsigned short*)d_ws;
  unsigned short* wt  = use_xb ? (unsigned short*)((char*)d_ws + xb_bytes)
                               : (unsigned short*)d_ws;
  float* pp = (float*)((char*)wt + 131072);

  hipLaunchKernelGGL(prep_w, dim3(9), dim3(256), 0, stream,
                     W0, W1, W2, B0, G0, Q0, B1, G1, Q1, B2, G2, Q2, W3, wt, pp);
  if (use_xb) {
    hipLaunchKernelGGL(prep_x, dim3(1024), dim3(256), 0, stream, x, xbp, nX / 8);
    hipLaunchKernelGGL(edge_mlp<1>, dim3(blocks), dim3(256), 0, stream,
                       x, ei, B3, wt, pp, xbp, out, nE);
  } else {
    hipLaunchKernelGGL(edge_mlp<0>, dim3(blocks), dim3(256), 0, stream,
                       x, ei, B3, wt, pp, xbp, out, nE);
  }
}

// Round 6
// 161.194 us; speedup vs baseline: 2.4106x; 1.2317x over previous
//
#include <hip/hip_runtime.h>
#include <hip/hip_bf16.h>

// EdgeNetwork R6: R5 structure (transposed-GEMM, K-permuted weights, hidden
// state in registers) with the spill fixed.
// R5 post-mortem: __launch_bounds__(256,4) caps VGPR+AGPR at 128; persistent
// state is acc(64 AGPR)+packed hidden(32)+transients -> ~50-reg spill/thread
// = 241 MB scratch writes + ~240 MB re-reads (WRITE_SIZE evidence, monotone
// across R3/R4/R5 caps). R6: (256,3) -> 170-reg cap, 12 waves/CU, no spill.

typedef float f32x4 __attribute__((ext_vector_type(4)));
typedef __bf16 bf16x8 __attribute__((ext_vector_type(8)));
typedef unsigned int u32x4 __attribute__((ext_vector_type(4)));

#define MFMA16(a, b, c) __builtin_amdgcn_mfma_f32_16x16x32_bf16((a), (b), (c), 0, 0, 0)

static __device__ __forceinline__ unsigned short bf16bits(float f) {
  __bf16 h = (__bf16)f;
  return __builtin_bit_cast(unsigned short, h);
}

static __device__ __forceinline__ unsigned pack2(float a, float b) {
  return (unsigned)bf16bits(a) | ((unsigned)bf16bits(b) << 16);
}

static __device__ __forceinline__ float tanh_fast(float t) {
  float ex = __expf(2.0f * t);
  return 1.0f - 2.0f * __builtin_amdgcn_rcpf(ex + 1.0f);
}

static __device__ __forceinline__ void gload_lds16(const void* g, void* l) {
  __builtin_amdgcn_global_load_lds(
      (const __attribute__((address_space(1))) void*)g,
      (__attribute__((address_space(3))) void*)l, 16, 0, 0);
}

// K-row permutation for layer>=1 weights (within each 32-row block):
// k = blk + g*8 + j  ->  blk + (j>>2)*16 + g*4 + (j&3)
static __device__ __forceinline__ int permk(int k) {
  const int j = k & 7, g = (k >> 3) & 3;
  return (k & ~31) | ((j >> 2) << 4) | (g << 2) | (j & 3);
}

// ---- prep: x (f32) -> xb (bf16) ----
__global__ void prep_x(const float* __restrict__ x,
                       unsigned short* __restrict__ xb, int n8) {
  int gid = blockIdx.x * blockDim.x + threadIdx.x;
  const int stride = gridDim.x * blockDim.x;
  for (int i = gid; i < n8; i += stride) {
    const float4 a = ((const float4*)x)[i * 2];
    const float4 b = ((const float4*)x)[i * 2 + 1];
    u32x4 o;
    o[0] = pack2(a.x, a.y); o[1] = pack2(a.z, a.w);
    o[2] = pack2(b.x, b.y); o[3] = pack2(b.z, b.w);
    ((u32x4*)xb)[i] = o;
  }
}

// ---- prep: weight slabs (swizzled, K-permuted for W1/W2) + param block ----
__global__ void prep_w(const float* __restrict__ W0, const float* __restrict__ W1,
                       const float* __restrict__ W2,
                       const float* __restrict__ B0, const float* __restrict__ G0,
                       const float* __restrict__ Q0,
                       const float* __restrict__ B1, const float* __restrict__ G1,
                       const float* __restrict__ Q1,
                       const float* __restrict__ B2, const float* __restrict__ G2,
                       const float* __restrict__ Q2,
                       const float* __restrict__ W3,
                       unsigned short* __restrict__ wt, float* __restrict__ pp) {
  const int t = blockIdx.x;
  const int tid = threadIdx.x;
  if (t == 8) {
    for (int i = tid; i < 1280; i += 256) {
      const int a = i >> 7, o = i & 127;
      float v;
      switch (a) {
        case 0: v = B0[o]; break;  case 1: v = G0[o]; break;
        case 2: v = Q0[o]; break;  case 3: v = B1[o]; break;
        case 4: v = G1[o]; break;  case 5: v = Q1[o]; break;
        case 6: v = B2[o]; break;  case 7: v = G2[o]; break;
        case 8: v = Q2[o]; break;  default: v = W3[o]; break;
      }
      pp[i] = v;
    }
    return;
  }
  const float* src; int kbase; int perm;
  if (t < 4)      { src = W0; kbase = t * 64;      perm = 0; }
  else if (t < 6) { src = W1; kbase = (t - 4) * 64; perm = 1; }
  else            { src = W2; kbase = (t - 6) * 64; perm = 1; }
  char* base = (char*)wt + t * 16384;
  const int col = tid & 127;
  const int kb  = (tid >> 7) << 1;
  #pragma unroll
  for (int i = 0; i < 16; ++i) {
    const int kl = kb + (i << 2);
    const int k0 = kbase + kl;
    const int c0 = perm ? permk(k0) : k0;  // c(k0+1) == c0+1 (k0 even)
    const float wa = src[c0 * 128 + col];
    const float wb = src[(c0 + 1) * 128 + col];
    const unsigned pk = pack2(wa, wb);
    const int off = ((col * 64 + kl) * 2) ^ ((col & 7) << 4);
    *(unsigned*)(base + off) = pk;
  }
}

#define P_B0 0
#define P_G0 128
#define P_Q0 256
#define P_B1 384
#define P_G1 512
#define P_Q1 640
#define P_B2 768
#define P_G2 896
#define P_Q2 1024
#define P_W3 1152

template <int XB>
__global__ __launch_bounds__(256, 3) void edge_mlp(
    const float* __restrict__ x, const int* __restrict__ ei,
    const float* __restrict__ B3,
    const unsigned short* __restrict__ wt, const float* __restrict__ pp,
    const unsigned short* __restrict__ xb,
    float* __restrict__ out, int nE)
{
  __shared__ __align__(16) char lds[32768 + 5120];
  float* plds = (float*)(lds + 32768);
  const int tid  = threadIdx.x;
  const int lane = tid & 63;
  const int wv   = tid >> 6;
  const int e    = lane & 15;  // edge within tile (N dim)
  const int g    = lane >> 4;  // k-group / accumulator row group

  const int wbase = blockIdx.x * 128 + wv * 32;
  const int e0 = wbase + e;
  const int e1 = wbase + 16 + e;
  const int ec0 = e0 < nE ? e0 : nE - 1;
  const int ec1 = e1 < nE ? e1 : nE - 1;
  const int ns0 = ei[ec0], ne0 = ei[nE + ec0];
  const int ns1 = ei[ec1], ne1 = ei[nE + ec1];

  auto stageW = [&](int t, int buf) {
    #pragma unroll
    for (int c = 0; c < 4; ++c) {
      const int o = wv * 4096 + c * 1024;
      gload_lds16((const char*)wt + t * 16384 + o + lane * 16,
                  lds + buf * 16384 + o);
    }
  };

  auto loadW = [&](int buf, int m, int kl) -> bf16x8 {
    const int col = m * 16 + e;
    const int off = ((col * 64 + kl) * 2) ^ ((col & 7) << 4);
    return *(const bf16x8*)(lds + buf * 16384 + off);
  };

  auto loadX = [&](int node, int ko) -> bf16x8 {
    if (XB) {
      return *(const bf16x8*)(xb + (size_t)node * 128 + ko);
    } else {
      const float* src = x + (size_t)node * 128 + ko;
      const float4 ua = *(const float4*)(src);
      const float4 ub = *(const float4*)(src + 4);
      bf16x8 a;
      a[0] = (__bf16)ua.x; a[1] = (__bf16)ua.y; a[2] = (__bf16)ua.z; a[3] = (__bf16)ua.w;
      a[4] = (__bf16)ub.x; a[5] = (__bf16)ub.y; a[6] = (__bf16)ub.z; a[7] = (__bf16)ub.w;
      return a;
    }
  };

  f32x4 acc[8][2];

  auto initAcc = [&](int pb) {
    #pragma unroll
    for (int m = 0; m < 8; ++m) {
      const f32x4 bq = *(const f32x4*)(plds + pb + m * 16 + g * 4);
      acc[m][0] = bq; acc[m][1] = bq;
    }
  };

  auto l0step = [&](int u0, int buf) {
    #pragma unroll
    for (int du = 0; du < 2; ++du) {
      const int u = u0 + du;
      const int ko = (u & 3) * 32 + g * 8;
      const bf16x8 xf0 = loadX(u < 4 ? ns0 : ne0, ko);
      const bf16x8 xf1 = loadX(u < 4 ? ns1 : ne1, ko);
      const int kl = du * 32 + g * 8;
      #pragma unroll
      for (int m = 0; m < 8; ++m) {
        const bf16x8 wf = loadW(buf, m, kl);
        acc[m][0] = MFMA16(wf, xf0, acc[m][0]);
        acc[m][1] = MFMA16(wf, xf1, acc[m][1]);
      }
    }
  };

  unsigned p0[2][8], p1[2][8];

  auto epi = [&](int pg, int pq) {
    #pragma unroll
    for (int j = 0; j < 2; ++j) {
      float s1 = 0.f, s2 = 0.f;
      #pragma unroll
      for (int m = 0; m < 8; ++m)
        #pragma unroll
        for (int r = 0; r < 4; ++r) {
          const float t = acc[m][j][r];
          s1 += t;
          s2 = __builtin_fmaf(t, t, s2);
        }
      s1 += __shfl_xor(s1, 16); s2 += __shfl_xor(s2, 16);
      s1 += __shfl_xor(s1, 32); s2 += __shfl_xor(s2, 32);
      const float mu  = s1 * 0.0078125f;
      const float inv = __builtin_amdgcn_rsqf(s2 * 0.0078125f - mu * mu + 1e-5f);
      #pragma unroll
      for (int m = 0; m < 8; ++m) {
        const f32x4 gq = *(const f32x4*)(plds + pg + m * 16 + g * 4);
        const f32x4 qq = *(const f32x4*)(plds + pq + m * 16 + g * 4);
        float th[4];
        #pragma unroll
        for (int r = 0; r < 4; ++r) {
          const float y = __builtin_fmaf(acc[m][j][r] - mu, inv * gq[r], qq[r]);
          th[r] = tanh_fast(y);
        }
        p0[j][m] = pack2(th[0], th[1]);
        p1[j][m] = pack2(th[2], th[3]);
      }
    }
  };

  auto lstep = [&](int u0, int buf) {
    #pragma unroll
    for (int du = 0; du < 2; ++du) {
      const int u = u0 + du;
      const int kl = du * 32 + g * 8;
      u32x4 w0, w1;
      w0[0] = p0[0][2 * u];     w0[1] = p1[0][2 * u];
      w0[2] = p0[0][2 * u + 1]; w0[3] = p1[0][2 * u + 1];
      w1[0] = p0[1][2 * u];     w1[1] = p1[1][2 * u];
      w1[2] = p0[1][2 * u + 1]; w1[3] = p1[1][2 * u + 1];
      const bf16x8 bf0 = __builtin_bit_cast(bf16x8, w0);
      const bf16x8 bf1 = __builtin_bit_cast(bf16x8, w1);
      #pragma unroll
      for (int m = 0; m < 8; ++m) {
        const bf16x8 wf = loadW(buf, m, kl);
        acc[m][0] = MFMA16(wf, bf0, acc[m][0]);
        acc[m][1] = MFMA16(wf, bf1, acc[m][1]);
      }
    }
  };

  // ---------------- schedule (8 barriers, dbuf slabs) ----------------
  stageW(0, 0);
  for (int i = tid; i < 1280; i += 256) plds[i] = pp[i];
  __syncthreads();

  initAcc(P_B0);
  stageW(1, 1); l0step(0, 0); __syncthreads();
  stageW(2, 0); l0step(2, 1); __syncthreads();
  stageW(3, 1); l0step(4, 0); __syncthreads();
  stageW(4, 0); l0step(6, 1); __syncthreads();            // buf0 <- W1 k0-63
  stageW(5, 1);                                            // buf1 <- W1 k64-127
  epi(P_G0, P_Q0); initAcc(P_B1); lstep(0, 0); __syncthreads();
  stageW(6, 0);                                            // buf0 <- W2 k0-63
  lstep(2, 1); __syncthreads();
  stageW(7, 1);                                            // buf1 <- W2 k64-127
  epi(P_G1, P_Q1); initAcc(P_B2); lstep(0, 0); __syncthreads();
  lstep(2, 1);

  // ---- final: LN + tanh + dot W3 + b3, all in registers ----
  const float b3v = B3[0];
  #pragma unroll
  for (int j = 0; j < 2; ++j) {
    float s1 = 0.f, s2 = 0.f;
    #pragma unroll
    for (int m = 0; m < 8; ++m)
      #pragma unroll
      for (int r = 0; r < 4; ++r) {
        const float t = acc[m][j][r];
        s1 += t;
        s2 = __builtin_fmaf(t, t, s2);
      }
    s1 += __shfl_xor(s1, 16); s2 += __shfl_xor(s2, 16);
    s1 += __shfl_xor(s1, 32); s2 += __shfl_xor(s2, 32);
    const float mu  = s1 * 0.0078125f;
    const float inv = __builtin_amdgcn_rsqf(s2 * 0.0078125f - mu * mu + 1e-5f);
    float d = 0.f;
    #pragma unroll
    for (int m = 0; m < 8; ++m) {
      const f32x4 gq  = *(const f32x4*)(plds + P_G2 + m * 16 + g * 4);
      const f32x4 qq  = *(const f32x4*)(plds + P_Q2 + m * 16 + g * 4);
      const f32x4 w3q = *(const f32x4*)(plds + P_W3 + m * 16 + g * 4);
      #pragma unroll
      for (int r = 0; r < 4; ++r) {
        const float y = __builtin_fmaf(acc[m][j][r] - mu, inv * gq[r], qq[r]);
        d = __builtin_fmaf(tanh_fast(y), w3q[r], d);
      }
    }
    d += __shfl_xor(d, 16);
    d += __shfl_xor(d, 32);
    const int eid = wbase + j * 16 + e;
    if (g == 0 && eid < nE) out[eid] = d + b3v;
  }
}

extern "C" void kernel_launch(void* const* d_in, const int* in_sizes, int n_in,
                              void* d_out, int out_size, void* d_ws, size_t ws_size,
                              hipStream_t stream) {
  const float* x  = (const float*)d_in[0];
  const int*   ei = (const int*)d_in[1];
  const float* W0 = (const float*)d_in[2];
  const float* B0 = (const float*)d_in[3];
  const float* W1 = (const float*)d_in[4];
  const float* B1 = (const float*)d_in[5];
  const float* W2 = (const float*)d_in[6];
  const float* B2 = (const float*)d_in[7];
  const float* W3 = (const float*)d_in[8];
  const float* B3 = (const float*)d_in[9];
  const float* G0 = (const float*)d_in[10];
  const float* Q0 = (const float*)d_in[11];
  const float* G1 = (const float*)d_in[12];
  const float* Q1 = (const float*)d_in[13];
  const float* G2 = (const float*)d_in[14];
  const float* Q2 = (const float*)d_in[15];
  float* out = (float*)d_out;

  const int nX = in_sizes[0];
  const int nE = in_sizes[1] / 2;
  const int blocks = (nE + 127) / 128;

  const size_t xb_bytes = ((size_t)nX * 2 + 255) & ~(size_t)255;
  const int use_xb = (ws_size >= xb_bytes + 131072 + 5120) ? 1 : 0;

  unsigned short* xbp = (unsigned short*)d_ws;
  unsigned short* wt  = use_xb ? (unsigned short*)((char*)d_ws + xb_bytes)
                               : (unsigned short*)d_ws;
  float* pp = (float*)((char*)wt + 131072);

  hipLaunchKernelGGL(prep_w, dim3(9), dim3(256), 0, stream,
                     W0, W1, W2, B0, G0, Q0, B1, G1, Q1, B2, G2, Q2, W3, wt, pp);
  if (use_xb) {
    hipLaunchKernelGGL(prep_x, dim3(1024), dim3(256), 0, stream, x, xbp, nX / 8);
    hipLaunchKernelGGL(edge_mlp<1>, dim3(blocks), dim3(256), 0, stream,
                       x, ei, B3, wt, pp, xbp, out, nE);
  } else {
    hipLaunchKernelGGL(edge_mlp<0>, dim3(blocks), dim3(256), 0, stream,
                       x, ei, B3, wt, pp, xbp, out, nE);
  }
}